// Round 4
// baseline (23863.797 us; speedup 1.0000x reference)
//
#include <hip/hip_runtime.h>
#include <math.h>

using u16 = unsigned short;
using u32 = unsigned int;

__device__ __forceinline__ float b2f(u16 u){
  union { u32 i; float f; } x; x.i = ((u32)u) << 16; return x.f;
}
__device__ __forceinline__ u16 f2b(float f){   // round-to-nearest-even
  union { float f; u32 i; } x; x.f = f;
  u32 i = x.i;
  u32 r = (i + 0x7fffu + ((i >> 16) & 1u)) >> 16;
  return (u16)r;
}

// ---------------- canary (only when ws too small): err encodes ws MB ----------------
__global__ __launch_bounds__(256) void canary_k(float* out, float code){
  out[threadIdx.x] = code;
}

// ---------------- f32 GEMM: C[M,N] = act(A[M,K] @ W[K,N] + b) ----------------
// AMODE 0: A is f32; 1: A is internal bf16 (u16). ACT 0: none; 1: relu; 2: sigmoid(relu(x)).
// Writes f32 to Cf (if non-null) and internal bf16 to Cb (if non-null).
template<int ACT, int AMODE>
__global__ __launch_bounds__(256) void gemm_f32(
    const void* __restrict__ Av, const float* __restrict__ W, const float* __restrict__ bias,
    int M, int K, int N, float* __restrict__ Cf, u16* __restrict__ Cb)
{
  __shared__ float As[64][33];
  __shared__ float Ws[32][65];
  const int t  = threadIdx.x;
  const int n0 = blockIdx.x * 64, m0 = blockIdx.y * 64;
  const int tx = t & 15, ty = t >> 4;
  const float* Af = (const float*)Av;
  const u16*   Ab = (const u16*)Av;
  float acc[4][4] = {};

  for (int k0 = 0; k0 < K; k0 += 32){
    for (int q = 0; q < 8; q++){            // stage A 64x32
      int e = q * 256 + t; int r = e >> 5, c = e & 31;
      float v = 0.f;
      if (k0 + c < K){
        size_t off = (size_t)(m0 + r) * K + k0 + c;
        v = AMODE ? b2f(Ab[off]) : Af[off];
      }
      As[r][c] = v;
    }
    for (int q = 0; q < 8; q++){            // stage W 32x64
      int e = q * 256 + t; int kr = e >> 6, c = e & 63;
      float v = 0.f;
      if (k0 + kr < K && n0 + c < N)
        v = W[(size_t)(k0 + kr) * N + n0 + c];
      Ws[kr][c] = v;
    }
    __syncthreads();
    for (int kk = 0; kk < 32; kk++){
      float a[4], w[4];
      #pragma unroll
      for (int r = 0; r < 4; r++) a[r] = As[ty * 4 + r][kk];
      #pragma unroll
      for (int c = 0; c < 4; c++) w[c] = Ws[kk][tx * 4 + c];
      #pragma unroll
      for (int r = 0; r < 4; r++)
        #pragma unroll
        for (int c = 0; c < 4; c++) acc[r][c] += a[r] * w[c];
    }
    __syncthreads();
  }

  for (int c = 0; c < 4; c++){
    int n = n0 + tx * 4 + c;
    if (n >= N) continue;
    float bv = bias[n];
    for (int r = 0; r < 4; r++){
      int m = m0 + ty * 4 + r;
      float v = acc[r][c] + bv;
      if (ACT >= 1) v = v > 0.f ? v : 0.f;
      if (ACT == 2) v = 1.f / (1.f + expf(-v));
      size_t off = (size_t)m * N + n;
      if (Cf) Cf[off] = v;
      if (Cb) Cb[off] = f2b(v);
    }
  }
}

// ---------------- row norms (rows x 128, f32) ----------------
__global__ __launch_bounds__(256) void norms_k(const float* __restrict__ src, float* __restrict__ out, int rows){
  int i = blockIdx.x * 256 + threadIdx.x;
  if (i >= rows) return;
  const float4* r = (const float4*)(src + (size_t)i * 128);
  float s = 0.f;
  for (int k = 0; k < 32; k++){
    float4 p = r[k];
    s += p.x * p.x + p.y * p.y + p.z * p.z + p.w * p.w;
  }
  out[i] = s;
}

// ---------------- row argmin: per query i, nearest codebook j ----------------
// 64 queries/block staged in LDS; 4 threads per query split the j-range (ascending
// ranges => cross-thread tie pick of lowest s preserves np first-wins).
__global__ __launch_bounds__(256) void rowmin_k(
    const float* __restrict__ z, const float* __restrict__ cb,
    const float* __restrict__ q2, const float* __restrict__ t2,
    int* __restrict__ rowidx, float* __restrict__ zdec)
{
  __shared__ float zl[64][129];
  __shared__ float sv[256];
  __shared__ int   sj[256];
  __shared__ int   jfin[64];
  const int t = threadIdx.x;
  const int i0 = blockIdx.x * 64;

  for (int q = 0; q < 32; q++){
    int e = q * 256 + t; int r = e >> 7, c = e & 127;
    zl[r][c] = z[(size_t)(i0 + r) * 128 + c];
  }
  __syncthreads();

  const int il = t >> 2, s = t & 3;
  const float q2i = q2[i0 + il];
  float best = 3.4e38f; int bj = s * 2048;
  for (int jj = 0; jj < 2048; jj++){
    int j = s * 2048 + jj;
    const float4* cr = (const float4*)(cb + (size_t)j * 128);
    float dot = 0.f;
    for (int k = 0; k < 32; k++){
      float4 p = cr[k];
      dot += p.x * zl[il][4*k] + p.y * zl[il][4*k+1] + p.z * zl[il][4*k+2] + p.w * zl[il][4*k+3];
    }
    float v = (q2i - 2.f * dot) + t2[j];
    if (v < best){ best = v; bj = j; }      // strict < => lowest j within range
  }
  sv[t] = best; sj[t] = bj;
  __syncthreads();
  if (s == 0){
    float bv = sv[t]; int j = sj[t];
    for (int ss = 1; ss < 4; ss++){
      float ov = sv[t + ss];
      if (ov < bv){ bv = ov; j = sj[t + ss]; }   // tie keeps lower range
    }
    j = j < 0 ? 0 : (j > 8191 ? 8191 : j);
    jfin[il] = j;
    rowidx[i0 + il] = j;
  }
  __syncthreads();
  for (int q = 0; q < 32; q++){
    int e = q * 256 + t; int r = e >> 7, c = e & 127;
    zdec[(size_t)(i0 + r) * 128 + c] = cb[(size_t)jfin[r] * 128 + c];
  }
}

// ---------------- col argmin: per codebook j, nearest query i ----------------
__global__ __launch_bounds__(256) void colmin_k(
    const float* __restrict__ z, const float* __restrict__ cb,
    const float* __restrict__ q2, const float* __restrict__ t2,
    float* __restrict__ zembd)
{
  __shared__ float cl[64][129];
  __shared__ float sv[256];
  __shared__ int   si[256];
  __shared__ int   ifin[64];
  const int t = threadIdx.x;
  const int j0 = blockIdx.x * 64;

  for (int q = 0; q < 32; q++){
    int e = q * 256 + t; int r = e >> 7, c = e & 127;
    cl[r][c] = cb[(size_t)(j0 + r) * 128 + c];
  }
  __syncthreads();

  const int jl = t >> 2, s = t & 3;
  const float t2j = t2[j0 + jl];
  float best = 3.4e38f; int bi = s * 4096;
  for (int ii = 0; ii < 4096; ii++){
    int i = s * 4096 + ii;
    const float4* zr = (const float4*)(z + (size_t)i * 128);
    float dot = 0.f;
    for (int k = 0; k < 32; k++){
      float4 p = zr[k];
      dot += p.x * cl[jl][4*k] + p.y * cl[jl][4*k+1] + p.z * cl[jl][4*k+2] + p.w * cl[jl][4*k+3];
    }
    float v = (t2j - 2.f * dot) + q2[i];   // query=codebook per ref
    if (v < best){ best = v; bi = i; }
  }
  sv[t] = best; si[t] = bi;
  __syncthreads();
  if (s == 0){
    float bv = sv[t]; int i = si[t];
    for (int ss = 1; ss < 4; ss++){
      float ov = sv[t + ss];
      if (ov < bv){ bv = ov; i = si[t + ss]; }
    }
    i = i < 0 ? 0 : (i > 16383 ? 16383 : i);
    ifin[jl] = i;
  }
  __syncthreads();
  for (int q = 0; q < 32; q++){
    int e = q * 256 + t; int r = e >> 7, c = e & 127;
    zembd[(size_t)(j0 + r) * 128 + c] = z[(size_t)ifin[r] * 128 + c];
  }
}

// ---------------- x_recon[i,:] = upcast(xdecb[rowidx[i],:]) ----------------
__global__ __launch_bounds__(256) void gather_xrec(
    const u16* __restrict__ xdecb, const int* __restrict__ rowidx, float* __restrict__ xrec)
{
  size_t o = (size_t)blockIdx.x * 256 + threadIdx.x;  // < 16384*784
  int row = (int)(o / 784), c = (int)(o % 784);
  int idx = rowidx[row];
  idx = idx < 0 ? 0 : (idx > 8191 ? 8191 : idx);
  xrec[o] = b2f(xdecb[(size_t)idx * 784 + c]);
}

// ---------------- launcher ----------------
extern "C" void kernel_launch(void* const* d_in, const int* in_sizes, int n_in,
                              void* d_out, int out_size, void* d_ws, size_t ws_size,
                              hipStream_t stream){
  const float* X   = (const float*)d_in[0];
  const float* w1  = (const float*)d_in[1];  const float* b1  = (const float*)d_in[2];
  const float* w2  = (const float*)d_in[3];  const float* b2  = (const float*)d_in[4];
  const float* w3  = (const float*)d_in[5];  const float* b3  = (const float*)d_in[6];
  const float* cb  = (const float*)d_in[7];
  const float* dw1 = (const float*)d_in[8];  const float* db1 = (const float*)d_in[9];
  const float* dw2 = (const float*)d_in[10]; const float* db2 = (const float*)d_in[11];
  const float* dw3 = (const float*)d_in[12]; const float* db3 = (const float*)d_in[13];

  float* out   = (float*)d_out;
  float* xrec  = out;                        // [16384*784]
  float* zenc  = out + 12845056;             // [16384*128]
  float* zdec  = zenc + 2097152;             // [16384*128]
  float* zembd = zdec + 2097152;             // [8192*128]

  const size_t NEEDED = 29786112;
  if (ws_size < NEEDED){
    canary_k<<<1, 256, 0, stream>>>(out, 1000.0f + (float)(ws_size >> 20));
    return;
  }

  char* w = (char*)d_ws;
  float* h1c   = (float*)(w + 0);            // 4096*512*4 = 8,388,608 (per-chunk; dead after enc)
  float* h2c   = (float*)(w + 8388608);      // 4096*256*4 = 4,194,304 (dead after enc)
  float* g1    = (float*)(w + 0);            // 8192*256*4 = 8,388,608 (decoder; reuses h1c)
  u16*   g2b   = (u16*)(w + 8388608);        // 8192*512*2 = 8,388,608 (reuses h2c+)
  u16*   xdecb = (u16*)(w + 16777216);       // 8192*784*2 = 12,845,056
  float* q2f   = (float*)(w + 29622272);     // 65,536
  float* t2f   = (float*)(w + 29687808);     // 32,768
  int*   rowi  = (int*)(w + 29720576);       // 65,536

  // encoder: 4 chunks of 4096 rows, full f32 (z written straight into d_out zenc)
  for (int c = 0; c < 4; c++){
    const float* Xc = X + (size_t)c * 4096 * 784;
    float* zc = zenc + (size_t)c * 4096 * 128;
    gemm_f32<1, 0><<<dim3(8, 64), 256, 0, stream>>>(Xc,  w1, b1, 4096, 784, 512, h1c, nullptr);
    gemm_f32<1, 0><<<dim3(4, 64), 256, 0, stream>>>(h1c, w2, b2, 4096, 512, 256, h2c, nullptr);
    gemm_f32<0, 0><<<dim3(2, 64), 256, 0, stream>>>(h2c, w3, b3, 4096, 256, 128, zc,  nullptr);
  }

  // norms
  norms_k<<<64, 256, 0, stream>>>(zenc, q2f, 16384);
  norms_k<<<32, 256, 0, stream>>>(cb,   t2f, 8192);

  // argmins (+ fused gathers of zdec / zembd, all f32)
  rowmin_k<<<256, 256, 0, stream>>>(zenc, cb, q2f, t2f, rowi, zdec);
  colmin_k<<<128, 256, 0, stream>>>(zenc, cb, q2f, t2f, zembd);

  // decoder over the 8192 codebook rows (bf16 internal g2/xdec), then gather
  gemm_f32<1, 0><<<dim3( 4, 128), 256, 0, stream>>>(cb,  dw1, db1, 8192, 128, 256, g1, nullptr);
  gemm_f32<1, 0><<<dim3( 8, 128), 256, 0, stream>>>(g1,  dw2, db2, 8192, 256, 512, nullptr, g2b);
  gemm_f32<2, 1><<<dim3(13, 128), 256, 0, stream>>>(g2b, dw3, db3, 8192, 512, 784, nullptr, xdecb);

  gather_xrec<<<50176, 256, 0, stream>>>(xdecb, rowi, xrec);
}

// Round 5
// 1939.793 us; speedup vs baseline: 12.3022x; 12.3022x over previous
//
#include <hip/hip_runtime.h>
#include <math.h>

using u16 = unsigned short;
using u32 = unsigned int;
using u64 = unsigned long long;

typedef __bf16 bf16x8 __attribute__((ext_vector_type(8)));
typedef short  s16x8  __attribute__((ext_vector_type(8)));
typedef float  f32x4  __attribute__((ext_vector_type(4)));

__device__ __forceinline__ float b2f(u16 u){
  union { u32 i; float f; } x; x.i = ((u32)u) << 16; return x.f;
}
__device__ __forceinline__ u16 f2b(float f){   // round-to-nearest-even
  union { float f; u32 i; } x; x.f = f;
  u32 i = x.i;
  u32 r = (i + 0x7fffu + ((i >> 16) & 1u)) >> 16;
  return (u16)r;
}
__device__ __forceinline__ f32x4 mfma16(s16x8 a, s16x8 b, f32x4 c){
  return __builtin_amdgcn_mfma_f32_16x16x32_bf16(
      __builtin_bit_cast(bf16x8, a), __builtin_bit_cast(bf16x8, b), c, 0, 0, 0);
}
__device__ __forceinline__ u64 shfl_xor_u64(u64 v, int m){
  int lo = __shfl_xor((int)(u32)v, m);
  int hi = __shfl_xor((int)(u32)(v >> 32), m);
  return ((u64)(u32)hi << 32) | (u32)lo;
}
__device__ __forceinline__ u64 umin64(u64 a, u64 b){ return a < b ? a : b; }
// sortable float pack: smaller d2 -> smaller u64; ties -> smaller index (np first-wins)
__device__ __forceinline__ u64 packmin(float v, int idx){
  u32 b = __float_as_uint(v);
  b = (b & 0x80000000u) ? ~b : (b | 0x80000000u);
  return ((u64)b << 32) | (u32)idx;
}

// ---------------- canary ----------------
__global__ __launch_bounds__(256) void canary_k(float* out, float code){
  out[threadIdx.x] = code;
}

// ---------------- f32 -> hi/lo bf16 split (elementwise) ----------------
__global__ __launch_bounds__(256) void split_k(const float* __restrict__ src,
                                               u16* __restrict__ hi, u16* __restrict__ lo, int n){
  int i = blockIdx.x * 256 + threadIdx.x;
  if (i >= n) return;
  float v = src[i];
  u16 h = f2b(v);
  hi[i] = h;
  lo[i] = f2b(v - b2f(h));
}

// W [K][N] f32 -> hi/lo [N][Kp] bf16, zero pad K..Kp
__global__ __launch_bounds__(256) void transpose_split(const float* __restrict__ in,
                                                       u16* __restrict__ hi, u16* __restrict__ lo,
                                                       int K, int N, int Kp){
  const size_t tot = (size_t)N * Kp;
  for (size_t o = (size_t)blockIdx.x * 256 + threadIdx.x; o < tot; o += (size_t)gridDim.x * 256){
    int n = (int)(o / Kp), kp = (int)(o % Kp);
    u16 h = 0, l = 0;
    if (kp < K){
      float v = in[(size_t)kp * N + n];
      h = f2b(v);
      l = f2b(v - b2f(h));
    }
    hi[o] = h; lo[o] = l;
  }
}

// ---------------- row norms (rows x 128, f32) ----------------
__global__ __launch_bounds__(256) void norms_k(const float* __restrict__ src, float* __restrict__ out, int rows){
  int i = blockIdx.x * 256 + threadIdx.x;
  if (i >= rows) return;
  const float4* r = (const float4*)(src + (size_t)i * 128);
  float s = 0.f;
  for (int k = 0; k < 32; k++){
    float4 p = r[k];
    s += p.x * p.x + p.y * p.y + p.z * p.z + p.w * p.w;
  }
  out[i] = s;
}

// ---------------- split-bf16 MFMA GEMM: C[M,N] = act(A @ B^T + bias) ----------------
// A planes (hi/lo) [M][Astr], valid k < KLIM; B planes [nRowsB][Kp].
// Product schedule: s in [0,nS), use A-lo if (schedA>>s)&1, B-lo if (schedB>>s)&1.
// ACT: 0 none, 1 relu, 2 sigmoid(relu). OUT: 0 planes (C0,C1); 1 f32 Cf + planes; 2 single bf16 C0.
template<int ACT, int OUT>
__global__ __launch_bounds__(256) void gemm_bt(
    const u16* __restrict__ A0, const u16* __restrict__ A1,
    const u16* __restrict__ B0, const u16* __restrict__ B1,
    const float* __restrict__ bias,
    float* __restrict__ Cf, u16* __restrict__ C0, u16* __restrict__ C1,
    int Astr, int KLIM, int Kp, int KT, int nS, int schedA, int schedB,
    int N, int nRowsB)
{
  __shared__ __align__(16) u16 As[128][72];
  __shared__ __align__(16) u16 Bs[128][72];
  const int tid = threadIdx.x;
  const int m0 = blockIdx.y * 128, n0 = blockIdx.x * 128;
  const int wave = tid >> 6, lane = tid & 63;
  const int wm = (wave >> 1) * 64, wn = (wave & 1) * 64;
  const int quad = lane >> 4, l15 = lane & 15;
  f32x4 acc[4][4] = {};

  const int itTot = nS * KT;
  for (int it = 0; it < itTot; ++it){
    const int s = it / KT;
    const int kb = (it - s * KT) * 64;
    const u16* aSrc = ((schedA >> s) & 1) ? A1 : A0;
    const u16* bSrc = ((schedB >> s) & 1) ? B1 : B0;
    #pragma unroll
    for (int c = 0; c < 4; c++){
      int idx = c * 256 + tid;
      int r = idx >> 3, col = (idx & 7) * 8;
      uint4 av = make_uint4(0, 0, 0, 0);
      if (kb + col < KLIM)
        av = *(const uint4*)(aSrc + (size_t)(m0 + r) * Astr + kb + col);
      int rb = n0 + r; rb = rb < nRowsB ? rb : nRowsB - 1;
      uint4 bv = *(const uint4*)(bSrc + (size_t)rb * Kp + kb + col);
      *(uint4*)(&As[r][col]) = av;
      *(uint4*)(&Bs[r][col]) = bv;
    }
    __syncthreads();
    s16x8 af[2][4], bfr[2][4];
    #pragma unroll
    for (int kh = 0; kh < 2; ++kh){
      #pragma unroll
      for (int t = 0; t < 4; t++){
        af[t == 0 ? kh : kh][t]  = *(const s16x8*)(&As[wm + t * 16 + l15][kh * 32 + quad * 8]);
        bfr[kh][t] = *(const s16x8*)(&Bs[wn + t * 16 + l15][kh * 32 + quad * 8]);
      }
    }
    #pragma unroll
    for (int mt = 0; mt < 4; mt++)
      #pragma unroll
      for (int nt = 0; nt < 4; nt++){
        acc[mt][nt] = mfma16(af[0][mt], bfr[0][nt], acc[mt][nt]);
        acc[mt][nt] = mfma16(af[1][mt], bfr[1][nt], acc[mt][nt]);
      }
    __syncthreads();
  }

  float bvs[4]; int cols[4];
  #pragma unroll
  for (int nt = 0; nt < 4; nt++){
    int cN = n0 + wn + nt * 16 + l15;
    cols[nt] = cN;
    int cc = cN < N ? cN : N - 1;
    bvs[nt] = bias[cc];
  }
  #pragma unroll
  for (int mt = 0; mt < 4; mt++){
    int rbase = m0 + wm + mt * 16 + quad * 4;
    #pragma unroll
    for (int nt = 0; nt < 4; nt++){
      if (cols[nt] < N){
        #pragma unroll
        for (int r = 0; r < 4; r++){
          float v = acc[mt][nt][r] + bvs[nt];
          if (ACT >= 1) v = v > 0.f ? v : 0.f;
          if (ACT == 2) v = 1.f / (1.f + expf(-v));
          size_t off = (size_t)(rbase + r) * N + cols[nt];
          if (OUT == 2){
            C0[off] = f2b(v);
          } else {
            if (OUT == 1) Cf[off] = v;
            u16 h = f2b(v);
            C0[off] = h;
            C1[off] = f2b(v - b2f(h));
          }
        }
      }
    }
  }
}

// ---------------- fused distance + dual argmin partials (split-bf16, 4 products) ----------------
// d2[i,j] = (q2[i] - 2*dot) + t2[j]; z planes [16384][128], cb planes [8192][128].
// rowp[jblk][16384], colp[iblk][8192] packed u64 partial minima.
__global__ __launch_bounds__(256) void dist_argmin(
    const u16* __restrict__ Zhi, const u16* __restrict__ Zlo,
    const u16* __restrict__ Bhi, const u16* __restrict__ Blo,
    const float* __restrict__ q2, const float* __restrict__ t2,
    u64* __restrict__ rowp, u64* __restrict__ colp)
{
  __shared__ __align__(16) u16 As[128][72];
  __shared__ __align__(16) u16 Bs[128][72];
  __shared__ u64 sRow[2][128];
  __shared__ u64 sCol[2][128];
  const int tid = threadIdx.x;
  const int i0 = blockIdx.y * 128, j0 = blockIdx.x * 128;
  const int wave = tid >> 6, lane = tid & 63;
  const int wm = (wave >> 1) * 64, wn = (wave & 1) * 64;
  const int quad = lane >> 4, l15 = lane & 15;
  f32x4 acc[4][4] = {};

  for (int it = 0; it < 8; ++it){
    const int s = it >> 1;
    const int kb = (it & 1) * 64;
    const u16* aSrc = (s >= 2) ? Zlo : Zhi;       // sched A: hi,hi,lo,lo
    const u16* bSrc = (s & 1) ? Blo : Bhi;        // sched B: hi,lo,hi,lo
    #pragma unroll
    for (int c = 0; c < 4; c++){
      int idx = c * 256 + tid;
      int r = idx >> 3, col = (idx & 7) * 8;
      uint4 av = *(const uint4*)(aSrc + (size_t)(i0 + r) * 128 + kb + col);
      uint4 bv = *(const uint4*)(bSrc + (size_t)(j0 + r) * 128 + kb + col);
      *(uint4*)(&As[r][col]) = av;
      *(uint4*)(&Bs[r][col]) = bv;
    }
    __syncthreads();
    s16x8 af[2][4], bfr[2][4];
    #pragma unroll
    for (int kh = 0; kh < 2; ++kh){
      #pragma unroll
      for (int t = 0; t < 4; t++){
        af[kh][t]  = *(const s16x8*)(&As[wm + t * 16 + l15][kh * 32 + quad * 8]);
        bfr[kh][t] = *(const s16x8*)(&Bs[wn + t * 16 + l15][kh * 32 + quad * 8]);
      }
    }
    #pragma unroll
    for (int mt = 0; mt < 4; mt++)
      #pragma unroll
      for (int nt = 0; nt < 4; nt++){
        acc[mt][nt] = mfma16(af[0][mt], bfr[0][nt], acc[mt][nt]);
        acc[mt][nt] = mfma16(af[1][mt], bfr[1][nt], acc[mt][nt]);
      }
    __syncthreads();
  }

  float t2v[4]; int gj[4];
  #pragma unroll
  for (int nt = 0; nt < 4; nt++){
    gj[nt] = j0 + wn + nt * 16 + l15;
    t2v[nt] = t2[gj[nt]];
  }
  u64 rowm[4][4], colm[4];
  #pragma unroll
  for (int mt = 0; mt < 4; mt++)
    #pragma unroll
    for (int r = 0; r < 4; r++) rowm[mt][r] = ~0ULL;
  #pragma unroll
  for (int nt = 0; nt < 4; nt++) colm[nt] = ~0ULL;

  #pragma unroll
  for (int mt = 0; mt < 4; mt++){
    #pragma unroll
    for (int r = 0; r < 4; r++){
      int gi = i0 + wm + mt * 16 + quad * 4 + r;
      float qv = q2[gi];
      #pragma unroll
      for (int nt = 0; nt < 4; nt++){
        float v = (qv - 2.f * acc[mt][nt][r]) + t2v[nt];
        rowm[mt][r] = umin64(rowm[mt][r], packmin(v, gj[nt]));
        // col direction: query=codebook -> (t2 - 2dot) + q2
        float vc = (t2v[nt] - 2.f * acc[mt][nt][r]) + qv;
        colm[nt]    = umin64(colm[nt],    packmin(vc, gi));
      }
    }
  }
  #pragma unroll
  for (int mt = 0; mt < 4; mt++)
    #pragma unroll
    for (int r = 0; r < 4; r++){
      u64 p = rowm[mt][r];
      p = umin64(p, shfl_xor_u64(p, 1));
      p = umin64(p, shfl_xor_u64(p, 2));
      p = umin64(p, shfl_xor_u64(p, 4));
      p = umin64(p, shfl_xor_u64(p, 8));
      rowm[mt][r] = p;
    }
  if (l15 == 0){
    #pragma unroll
    for (int mt = 0; mt < 4; mt++)
      #pragma unroll
      for (int r = 0; r < 4; r++)
        sRow[wave & 1][wm + mt * 16 + quad * 4 + r] = rowm[mt][r];
  }
  #pragma unroll
  for (int nt = 0; nt < 4; nt++){
    u64 p = colm[nt];
    p = umin64(p, shfl_xor_u64(p, 16));
    p = umin64(p, shfl_xor_u64(p, 32));
    colm[nt] = p;
  }
  if (quad == 0){
    #pragma unroll
    for (int nt = 0; nt < 4; nt++)
      sCol[wave >> 1][wn + nt * 16 + l15] = colm[nt];
  }
  __syncthreads();
  if (tid < 128){
    rowp[(size_t)blockIdx.x * 16384 + i0 + tid] = umin64(sRow[0][tid], sRow[1][tid]);
    colp[(size_t)blockIdx.y * 8192  + j0 + tid] = umin64(sCol[0][tid], sCol[1][tid]);
  }
}

// ---------------- final reduces + gathers (f32 rows of 128) ----------------
__global__ __launch_bounds__(256) void reduce_row(
    const u64* __restrict__ rowp, const float* __restrict__ cb,
    float* __restrict__ zdec, int* __restrict__ rowidx)
{
  int tid = threadIdx.x;
  int base = blockIdx.x * 64;
  int n = base + (tid & 63);
  u64 best = ~0ULL;
  for (int p = tid >> 6; p < 64; p += 4)
    best = umin64(best, rowp[(size_t)p * 16384 + n]);
  __shared__ u64 s[4][64];
  __shared__ int sidx[64];
  s[tid >> 6][tid & 63] = best;
  __syncthreads();
  if (tid < 64){
    u64 b = umin64(umin64(s[0][tid], s[1][tid]), umin64(s[2][tid], s[3][tid]));
    int idx = (int)(b & 0xffffffffULL);
    idx = idx < 0 ? 0 : (idx > 8191 ? 8191 : idx);
    sidx[tid] = idx;
    rowidx[base + tid] = idx;
  }
  __syncthreads();
  for (int q = 0; q < 32; q++){
    int e = q * 256 + tid; int r = e >> 7, c = e & 127;
    zdec[(size_t)(base + r) * 128 + c] = cb[(size_t)sidx[r] * 128 + c];
  }
}

__global__ __launch_bounds__(256) void reduce_col(
    const u64* __restrict__ colp, const float* __restrict__ zenc, float* __restrict__ zembd)
{
  int tid = threadIdx.x;
  int base = blockIdx.x * 64;
  int n = base + (tid & 63);
  u64 best = ~0ULL;
  for (int p = tid >> 6; p < 128; p += 4)
    best = umin64(best, colp[(size_t)p * 8192 + n]);
  __shared__ u64 s[4][64];
  __shared__ int sidx[64];
  s[tid >> 6][tid & 63] = best;
  __syncthreads();
  if (tid < 64){
    u64 b = umin64(umin64(s[0][tid], s[1][tid]), umin64(s[2][tid], s[3][tid]));
    int idx = (int)(b & 0xffffffffULL);
    idx = idx < 0 ? 0 : (idx > 16383 ? 16383 : idx);
    sidx[tid] = idx;
  }
  __syncthreads();
  for (int q = 0; q < 32; q++){
    int e = q * 256 + tid; int r = e >> 7, c = e & 127;
    zembd[(size_t)(base + r) * 128 + c] = zenc[(size_t)sidx[r] * 128 + c];
  }
}

// x_recon[i,:] = upcast(xdecb[rowidx[i],:])
__global__ __launch_bounds__(256) void gather_xrec(
    const u16* __restrict__ xdecb, const int* __restrict__ rowidx, float* __restrict__ xrec)
{
  size_t o = (size_t)blockIdx.x * 256 + threadIdx.x;  // < 16384*784
  int row = (int)(o / 784), c = (int)(o % 784);
  int idx = rowidx[row];
  idx = idx < 0 ? 0 : (idx > 8191 ? 8191 : idx);
  xrec[o] = b2f(xdecb[(size_t)idx * 784 + c]);
}

// ---------------- launcher ----------------
extern "C" void kernel_launch(void* const* d_in, const int* in_sizes, int n_in,
                              void* d_out, int out_size, void* d_ws, size_t ws_size,
                              hipStream_t stream){
  const float* X   = (const float*)d_in[0];
  const float* w1  = (const float*)d_in[1];  const float* b1  = (const float*)d_in[2];
  const float* w2  = (const float*)d_in[3];  const float* b2  = (const float*)d_in[4];
  const float* w3  = (const float*)d_in[5];  const float* b3  = (const float*)d_in[6];
  const float* cb  = (const float*)d_in[7];
  const float* dw1 = (const float*)d_in[8];  const float* db1 = (const float*)d_in[9];
  const float* dw2 = (const float*)d_in[10]; const float* db2 = (const float*)d_in[11];
  const float* dw3 = (const float*)d_in[12]; const float* db3 = (const float*)d_in[13];

  float* out   = (float*)d_out;
  float* xrec  = out;                        // [16384*784]
  float* zenc  = out + 12845056;             // [16384*128]
  float* zdec  = zenc + 2097152;             // [16384*128]
  float* zembd = zdec + 2097152;             // [8192*128]

  const size_t NEEDED = 32047104;            // proven ws_size >= 32,129,024 (round-2 canary silent)
  if (ws_size < NEEDED){
    canary_k<<<1, 256, 0, stream>>>(out, 1000.0f + (float)(ws_size >> 20));
    return;
  }

  char* w = (char*)d_ws;
  // persistent: cb planes [0,4.19M) live until decoder L1
  u16* cbhi = (u16*)(w + 0);                 // 2,097,152
  u16* cblo = (u16*)(w + 2097152);           // -> 4,194,304
  // z planes [4.19M,12.58M) live enc-L3 .. dist; then g1 planes (decoder)
  u16* zhi  = (u16*)(w + 4194304);           // 4,194,304
  u16* zlo  = (u16*)(w + 8388608);           // -> 12,582,912
  u16* g1hi = (u16*)(w + 4194304);
  u16* g1lo = (u16*)(w + 8388608);
  // encoder chunk scratch [12.58M,25.3M): Xc, h1c, h2c planes; then rowp; then (partially) g2
  u16* Xchi = (u16*)(w + 12582912);          // 2048*784*2 = 3,211,264
  u16* Xclo = (u16*)(w + 15794176);          // -> 19,005,440
  u16* h1hi = (u16*)(w + 19005440);          // 2,097,152
  u16* h1lo = (u16*)(w + 21102592);          // -> 23,199,744
  u16* h2hi = (u16*)(w + 23199744);          // 1,048,576
  u16* h2lo = (u16*)(w + 24248320);          // -> 25,296,896
  // encoder weight planes [25.3M,27.66M) — dead after encoder
  u16* W1Thi = (u16*)(w + 25296896);         // 851,968
  u16* W1Tlo = (u16*)(w + 26148864);         // -> 27,000,832
  u16* W2Thi = (u16*)(w + 27000832);         // 262,144
  u16* W2Tlo = (u16*)(w + 27262976);         // -> 27,525,120
  u16* W3Thi = (u16*)(w + 27525120);         // 65,536
  u16* W3Tlo = (u16*)(w + 27590656);         // -> 27,656,192
  // dist partials (after encoder dead regions)
  u64* rowp = (u64*)(w + 12582912);          // 8,388,608 -> 20,971,520
  u64* colp = (u64*)(w + 20971520);          // 8,388,608 -> 29,360,128
  // decoder: xdecb [0,12.85M) (cb/g1 dead by L3), g2 planes [12.85M,29.62M)
  u16* xdecb = (u16*)(w + 0);                // 8192*784*2 = 12,845,056
  u16* g2hi  = (u16*)(w + 12845056);         // 8,388,608
  u16* g2lo  = (u16*)(w + 21233664);         // -> 29,622,272
  // persistent tail [29.62M, 32.05M)
  u16* D1Thi = (u16*)(w + 29622272);         // 65,536
  u16* D1Tlo = (u16*)(w + 29687808);
  u16* D2Thi = (u16*)(w + 29753344);         // 262,144
  u16* D2Tlo = (u16*)(w + 30015488);
  u16* D3Thi = (u16*)(w + 30277632);         // 802,816
  u16* D3Tlo = (u16*)(w + 31080448);         // -> 31,883,264
  float* q2f = (float*)(w + 31883264);       // 65,536
  float* t2f = (float*)(w + 31948800);       // 32,768
  int*  rowi = (int*)(w + 31981568);         // 65,536 -> 32,047,104

  // weight + codebook splits
  transpose_split<<<1664, 256, 0, stream>>>(w1,  W1Thi, W1Tlo, 784, 512, 832);
  transpose_split<<< 512, 256, 0, stream>>>(w2,  W2Thi, W2Tlo, 512, 256, 512);
  transpose_split<<< 128, 256, 0, stream>>>(w3,  W3Thi, W3Tlo, 256, 128, 256);
  transpose_split<<< 128, 256, 0, stream>>>(dw1, D1Thi, D1Tlo, 128, 256, 128);
  transpose_split<<< 512, 256, 0, stream>>>(dw2, D2Thi, D2Tlo, 256, 512, 256);
  transpose_split<<<1568, 256, 0, stream>>>(dw3, D3Thi, D3Tlo, 512, 784, 512);
  split_k<<<4096, 256, 0, stream>>>(cb, cbhi, cblo, 8192 * 128);

  // encoder: 8 chunks of 2048 rows; 3-product split-bf16 MFMA (schedA=0b100, schedB=0b010)
  for (int c = 0; c < 8; c++){
    const float* Xc = X + (size_t)c * 2048 * 784;
    float* zc  = zenc + (size_t)c * 2048 * 128;
    u16* zch = zhi + (size_t)c * 2048 * 128;
    u16* zcl = zlo + (size_t)c * 2048 * 128;
    split_k<<<6272, 256, 0, stream>>>(Xc, Xchi, Xclo, 2048 * 784);
    gemm_bt<1, 0><<<dim3(4, 16), 256, 0, stream>>>(Xchi, Xclo, W1Thi, W1Tlo, b1,
        nullptr, h1hi, h1lo, 784, 784, 832, 13, 3, 4, 2, 512, 512);
    gemm_bt<1, 0><<<dim3(2, 16), 256, 0, stream>>>(h1hi, h1lo, W2Thi, W2Tlo, b2,
        nullptr, h2hi, h2lo, 512, 512, 512, 8, 3, 4, 2, 256, 256);
    gemm_bt<0, 1><<<dim3(1, 16), 256, 0, stream>>>(h2hi, h2lo, W3Thi, W3Tlo, b3,
        zc, zch, zcl, 256, 256, 256, 4, 3, 4, 2, 128, 128);
  }

  // norms (f32 sources)
  norms_k<<<64, 256, 0, stream>>>(zenc, q2f, 16384);
  norms_k<<<32, 256, 0, stream>>>(cb,   t2f, 8192);

  // fused distance + dual argmin (4-product split-bf16)
  dist_argmin<<<dim3(64, 128), 256, 0, stream>>>(zhi, zlo, cbhi, cblo, q2f, t2f, rowp, colp);

  // reduces + gathers (f32)
  reduce_row<<<256, 256, 0, stream>>>(rowp, cb, zdec, rowi);
  reduce_col<<<128, 256, 0, stream>>>(colp, zenc, zembd);

  // decoder over 8192 codebook rows (A = cb planes), then gather
  gemm_bt<1, 0><<<dim3(2, 64), 256, 0, stream>>>(cbhi, cblo, D1Thi, D1Tlo, db1,
      nullptr, g1hi, g1lo, 128, 128, 128, 2, 3, 4, 2, 256, 256);
  gemm_bt<1, 0><<<dim3(4, 64), 256, 0, stream>>>(g1hi, g1lo, D2Thi, D2Tlo, db2,
      nullptr, g2hi, g2lo, 256, 256, 256, 4, 3, 4, 2, 512, 512);
  gemm_bt<2, 2><<<dim3(7, 64), 256, 0, stream>>>(g2hi, g2lo, D3Thi, D3Tlo, db3,
      nullptr, xdecb, nullptr, 512, 512, 512, 8, 3, 4, 2, 784, 784);

  gather_xrec<<<50176, 256, 0, stream>>>(xdecb, rowi, xrec);
}

// Round 7
// 647.067 us; speedup vs baseline: 36.8800x; 2.9978x over previous
//
#include <hip/hip_runtime.h>
#include <math.h>

using u16 = unsigned short;
using u32 = unsigned int;
using u64 = unsigned long long;

typedef __bf16 bf16x8 __attribute__((ext_vector_type(8)));
typedef short  s16x8  __attribute__((ext_vector_type(8)));
typedef float  f32x4  __attribute__((ext_vector_type(4)));

__device__ __forceinline__ float b2f(u16 u){
  union { u32 i; float f; } x; x.i = ((u32)u) << 16; return x.f;
}
__device__ __forceinline__ u16 f2b(float f){   // round-to-nearest-even
  union { float f; u32 i; } x; x.f = f;
  u32 i = x.i;
  u32 r = (i + 0x7fffu + ((i >> 16) & 1u)) >> 16;
  return (u16)r;
}
__device__ __forceinline__ f32x4 mfma16(s16x8 a, s16x8 b, f32x4 c){
  return __builtin_amdgcn_mfma_f32_16x16x32_bf16(
      __builtin_bit_cast(bf16x8, a), __builtin_bit_cast(bf16x8, b), c, 0, 0, 0);
}
__device__ __forceinline__ u64 shfl_xor_u64(u64 v, int m){
  int lo = __shfl_xor((int)(u32)v, m);
  int hi = __shfl_xor((int)(u32)(v >> 32), m);
  return ((u64)(u32)hi << 32) | (u32)lo;
}
__device__ __forceinline__ u64 umin64(u64 a, u64 b){ return a < b ? a : b; }
__device__ __forceinline__ u64 packmin(float v, int idx){
  u32 b = __float_as_uint(v);
  b = (b & 0x80000000u) ? ~b : (b | 0x80000000u);
  return ((u64)b << 32) | (u32)idx;
}

// ---------------- canary ----------------
__global__ __launch_bounds__(256) void canary_k(float* out, float code){
  out[threadIdx.x] = code;
}

// ---------------- fused weight prep: 6 transposed hi/lo splits ----------------
// W [K][N] f32 -> [N][Kp] bf16 hi/lo planes, zero-pad K..Kp
__global__ __launch_bounds__(256) void prep_weights(
    const float* __restrict__ w1, const float* __restrict__ w2, const float* __restrict__ w3,
    const float* __restrict__ dw1, const float* __restrict__ dw2, const float* __restrict__ dw3,
    u16* __restrict__ o1h, u16* __restrict__ o1l, u16* __restrict__ o2h, u16* __restrict__ o2l,
    u16* __restrict__ o3h, u16* __restrict__ o3l, u16* __restrict__ o4h, u16* __restrict__ o4l,
    u16* __restrict__ o5h, u16* __restrict__ o5l, u16* __restrict__ o6h, u16* __restrict__ o6l)
{
  size_t o = (size_t)blockIdx.x * 256 + threadIdx.x;
  const float* src; u16 *hi, *lo; int K, N, Kp; size_t base;
  if      (o <  425984){ src=w1;  hi=o1h; lo=o1l; K=784; N=512; Kp=832; base=0; }
  else if (o <  557056){ src=w2;  hi=o2h; lo=o2l; K=512; N=256; Kp=512; base=425984; }
  else if (o <  589824){ src=w3;  hi=o3h; lo=o3l; K=256; N=128; Kp=256; base=557056; }
  else if (o <  622592){ src=dw1; hi=o4h; lo=o4l; K=128; N=256; Kp=128; base=589824; }
  else if (o <  753664){ src=dw2; hi=o5h; lo=o5l; K=256; N=512; Kp=256; base=622592; }
  else if (o < 1155072){ src=dw3; hi=o6h; lo=o6l; K=512; N=784; Kp=512; base=753664; }
  else return;
  size_t e = o - base;
  int n = (int)(e / Kp), kp = (int)(e % Kp);
  u16 h = 0, l = 0;
  if (kp < K){
    float v = src[(size_t)kp * N + n];
    h = f2b(v);
    l = f2b(v - b2f(h));
  }
  hi[e] = h; lo[e] = l;
}

// ---------------- cb f32 -> hi/lo planes ----------------
__global__ __launch_bounds__(256) void split_cb(const float* __restrict__ src,
                                                u16* __restrict__ hi, u16* __restrict__ lo){
  int i = blockIdx.x * 256 + threadIdx.x;   // < 8192*128
  float v = src[i];
  u16 h = f2b(v);
  hi[i] = h;
  lo[i] = f2b(v - b2f(h));
}

// ---------------- fused norms: q2 (z rows) + t2 (cb rows) ----------------
__global__ __launch_bounds__(256) void norms_all(const float* __restrict__ z, const float* __restrict__ cb,
                                                 float* __restrict__ q2, float* __restrict__ t2){
  int i = blockIdx.x * 256 + threadIdx.x;   // < 24576
  const float* src; float* dst;
  if (i < 16384){ src = z + (size_t)i * 128; dst = q2 + i; }
  else { int j = i - 16384; src = cb + (size_t)j * 128; dst = t2 + j; }
  const float4* r = (const float4*)src;
  float s = 0.f;
  for (int k = 0; k < 32; k++){
    float4 p = r[k];
    s += p.x * p.x + p.y * p.y + p.z * p.z + p.w * p.w;
  }
  *dst = s;
}

// ---------------- MFMA GEMM, A = f32 with on-the-fly hi/lo split ----------------
// C[M,N] = act(A @ B^T + bias); B pre-split planes [nRowsB][Kp].
// 3 products: Ahi*Bhi + Ahi*Blo + Alo*Bhi.
// ACT: 0 none, 1 relu, 2 sigmoid(relu). OUTP: 0 f32; 1 f32 + hi/lo planes; 2 bf16 only.
template<int ACT, int OUTP>
__global__ __launch_bounds__(256, 2) void gemm_af32(
    const float* __restrict__ A, const u16* __restrict__ B0, const u16* __restrict__ B1,
    const float* __restrict__ bias, float* __restrict__ Cf,
    u16* __restrict__ P0, u16* __restrict__ P1,
    int Astr, int KLIM, int Kp, int KT, int N, int nRowsB)
{
  __shared__ __align__(16) u16 Ah[128][72];
  __shared__ __align__(16) u16 Al[128][72];
  __shared__ __align__(16) u16 Bh[128][72];
  __shared__ __align__(16) u16 Bl[128][72];
  const int tid = threadIdx.x;
  const int m0 = blockIdx.y * 128, n0 = blockIdx.x * 128;
  const int wave = tid >> 6, lane = tid & 63;
  const int wm = (wave >> 1) * 64, wn = (wave & 1) * 64;
  const int quad = lane >> 4, l15 = lane & 15;
  f32x4 acc[4][4] = {};

  for (int kt = 0; kt < KT; ++kt){
    const int kb = kt * 64;
    #pragma unroll
    for (int c = 0; c < 8; c++){            // stage A: 128 x 64 f32, split hi/lo
      int idx = c * 256 + tid;
      int r = idx >> 4, c4 = (idx & 15) * 4;
      float4 v = make_float4(0.f, 0.f, 0.f, 0.f);
      if (kb + c4 < KLIM)
        v = *(const float4*)(A + (size_t)(m0 + r) * Astr + kb + c4);
      ushort4 h, l;
      h.x = f2b(v.x); l.x = f2b(v.x - b2f(h.x));
      h.y = f2b(v.y); l.y = f2b(v.y - b2f(h.y));
      h.z = f2b(v.z); l.z = f2b(v.z - b2f(h.z));
      h.w = f2b(v.w); l.w = f2b(v.w - b2f(h.w));
      *(ushort4*)&Ah[r][c4] = h;
      *(ushort4*)&Al[r][c4] = l;
    }
    #pragma unroll
    for (int c = 0; c < 4; c++){            // stage B planes: 128 x 64 u16 each
      int idx = c * 256 + tid;
      int r = idx >> 3, col = (idx & 7) * 8;
      int rb = n0 + r; rb = rb < nRowsB ? rb : nRowsB - 1;
      *(uint4*)&Bh[r][col] = *(const uint4*)(B0 + (size_t)rb * Kp + kb + col);
      *(uint4*)&Bl[r][col] = *(const uint4*)(B1 + (size_t)rb * Kp + kb + col);
    }
    __syncthreads();
    #pragma unroll
    for (int kh = 0; kh < 2; ++kh){
      s16x8 ah[4], al[4], bh[4], bl[4];
      #pragma unroll
      for (int t4 = 0; t4 < 4; t4++){
        ah[t4] = *(const s16x8*)&Ah[wm + t4 * 16 + l15][kh * 32 + quad * 8];
        al[t4] = *(const s16x8*)&Al[wm + t4 * 16 + l15][kh * 32 + quad * 8];
        bh[t4] = *(const s16x8*)&Bh[wn + t4 * 16 + l15][kh * 32 + quad * 8];
        bl[t4] = *(const s16x8*)&Bl[wn + t4 * 16 + l15][kh * 32 + quad * 8];
      }
      #pragma unroll
      for (int mt = 0; mt < 4; mt++)
        #pragma unroll
        for (int nt = 0; nt < 4; nt++){
          acc[mt][nt] = mfma16(ah[mt], bh[nt], acc[mt][nt]);
          acc[mt][nt] = mfma16(ah[mt], bl[nt], acc[mt][nt]);
          acc[mt][nt] = mfma16(al[mt], bh[nt], acc[mt][nt]);
        }
    }
    __syncthreads();
  }

  float bvs[4]; int cols[4];
  #pragma unroll
  for (int nt = 0; nt < 4; nt++){
    int cN = n0 + wn + nt * 16 + l15;
    cols[nt] = cN;
    int cc = cN < N ? cN : N - 1;
    bvs[nt] = bias[cc];
  }
  #pragma unroll
  for (int mt = 0; mt < 4; mt++){
    int rbase = m0 + wm + mt * 16 + quad * 4;
    #pragma unroll
    for (int nt = 0; nt < 4; nt++){
      if (cols[nt] < N){
        #pragma unroll
        for (int r = 0; r < 4; r++){
          float v = acc[mt][nt][r] + bvs[nt];
          if (ACT >= 1) v = v > 0.f ? v : 0.f;
          if (ACT == 2) v = 1.f / (1.f + expf(-v));
          size_t off = (size_t)(rbase + r) * N + cols[nt];
          if (OUTP == 2){
            P0[off] = f2b(v);
          } else {
            Cf[off] = v;
            if (OUTP == 1){
              u16 h = f2b(v);
              P0[off] = h;
              P1[off] = f2b(v - b2f(h));
            }
          }
        }
      }
    }
  }
}

// ---------------- dist v3: z frags in registers, cb frags from global planes ----------------
// grid (4 strips, 128 i-tiles); each block sweeps 16 j-tiles of 128 (strip stride 2048).
// 4 products (hh, hl, lh, ll) — bit-compatible value set with round 5.
__global__ __launch_bounds__(256, 1) void dist3(
    const u16* __restrict__ Zh, const u16* __restrict__ Zl,
    const u16* __restrict__ Bh, const u16* __restrict__ Bl,
    const float* __restrict__ q2, const float* __restrict__ t2,
    u64* __restrict__ rowp, u64* __restrict__ colp)
{
  __shared__ u64 sRow[2][128];
  __shared__ u64 sCol[2][128];
  const int tid = threadIdx.x;
  const int i0 = blockIdx.y * 128;
  const int strip = blockIdx.x;
  const int wave = tid >> 6, lane = tid & 63;
  const int wm = (wave >> 1) * 64, wn = (wave & 1) * 64;
  const int quad = lane >> 4, l15 = lane & 15;

  // z fragments, loaded once
  s16x8 zh[2][2][4], zl[2][2][4];
  #pragma unroll
  for (int kb = 0; kb < 2; kb++)
    #pragma unroll
    for (int kh = 0; kh < 2; kh++)
      #pragma unroll
      for (int mt = 0; mt < 4; mt++){
        size_t off = (size_t)(i0 + wm + mt * 16 + l15) * 128 + kb * 64 + kh * 32 + quad * 8;
        zh[kb][kh][mt] = *(const s16x8*)(Zh + off);
        zl[kb][kh][mt] = *(const s16x8*)(Zl + off);
      }
  float qv[4][4];
  #pragma unroll
  for (int mt = 0; mt < 4; mt++)
    #pragma unroll
    for (int r = 0; r < 4; r++)
      qv[mt][r] = q2[i0 + wm + mt * 16 + quad * 4 + r];

  u64 rowm[4][4];
  #pragma unroll
  for (int mt = 0; mt < 4; mt++)
    #pragma unroll
    for (int r = 0; r < 4; r++) rowm[mt][r] = ~0ULL;

  for (int jt = 0; jt < 16; ++jt){
    const int j0 = strip * 2048 + jt * 128;   // FIX (was strip*4096): 4 strips x 16 tiles x 128 = 8192
    f32x4 acc[4][4] = {};
    #pragma unroll
    for (int kb = 0; kb < 2; kb++)
      #pragma unroll
      for (int kh = 0; kh < 2; kh++){
        s16x8 bh[4], bl[4];
        #pragma unroll
        for (int nt = 0; nt < 4; nt++){
          size_t off = (size_t)(j0 + wn + nt * 16 + l15) * 128 + kb * 64 + kh * 32 + quad * 8;
          bh[nt] = *(const s16x8*)(Bh + off);
          bl[nt] = *(const s16x8*)(Bl + off);
        }
        #pragma unroll
        for (int mt = 0; mt < 4; mt++)
          #pragma unroll
          for (int nt = 0; nt < 4; nt++){
            acc[mt][nt] = mfma16(zh[kb][kh][mt], bh[nt], acc[mt][nt]);
            acc[mt][nt] = mfma16(zh[kb][kh][mt], bl[nt], acc[mt][nt]);
            acc[mt][nt] = mfma16(zl[kb][kh][mt], bh[nt], acc[mt][nt]);
            acc[mt][nt] = mfma16(zl[kb][kh][mt], bl[nt], acc[mt][nt]);
          }
      }
    // epilogue for this j-tile
    float t2v[4]; int gj[4];
    #pragma unroll
    for (int nt = 0; nt < 4; nt++){
      gj[nt] = j0 + wn + nt * 16 + l15;
      t2v[nt] = t2[gj[nt]];
    }
    u64 colm[4];
    #pragma unroll
    for (int nt = 0; nt < 4; nt++) colm[nt] = ~0ULL;
    #pragma unroll
    for (int mt = 0; mt < 4; mt++){
      #pragma unroll
      for (int r = 0; r < 4; r++){
        float qq = qv[mt][r];
        int gi = i0 + wm + mt * 16 + quad * 4 + r;
        #pragma unroll
        for (int nt = 0; nt < 4; nt++){
          float dot2 = 2.f * acc[mt][nt][r];
          float v  = (qq - dot2) + t2v[nt];
          rowm[mt][r] = umin64(rowm[mt][r], packmin(v, gj[nt]));
          float vc = (t2v[nt] - dot2) + qq;
          colm[nt] = umin64(colm[nt], packmin(vc, gi));
        }
      }
    }
    #pragma unroll
    for (int nt = 0; nt < 4; nt++){
      u64 p = colm[nt];
      p = umin64(p, shfl_xor_u64(p, 16));
      p = umin64(p, shfl_xor_u64(p, 32));
      colm[nt] = p;
    }
    __syncthreads();
    if (quad == 0){
      #pragma unroll
      for (int nt = 0; nt < 4; nt++)
        sCol[wave >> 1][wn + nt * 16 + l15] = colm[nt];
    }
    __syncthreads();
    if (tid < 128)
      colp[(size_t)blockIdx.y * 8192 + j0 + tid] = umin64(sCol[0][tid], sCol[1][tid]);
  }

  // row final reduce
  #pragma unroll
  for (int mt = 0; mt < 4; mt++)
    #pragma unroll
    for (int r = 0; r < 4; r++){
      u64 p = rowm[mt][r];
      p = umin64(p, shfl_xor_u64(p, 1));
      p = umin64(p, shfl_xor_u64(p, 2));
      p = umin64(p, shfl_xor_u64(p, 4));
      p = umin64(p, shfl_xor_u64(p, 8));
      rowm[mt][r] = p;
    }
  if (l15 == 0){
    #pragma unroll
    for (int mt = 0; mt < 4; mt++)
      #pragma unroll
      for (int r = 0; r < 4; r++)
        sRow[wave & 1][wm + mt * 16 + quad * 4 + r] = rowm[mt][r];
  }
  __syncthreads();
  if (tid < 128)
    rowp[(size_t)strip * 16384 + i0 + tid] = umin64(sRow[0][tid], sRow[1][tid]);
}

// ---------------- final reduces + gathers ----------------
__global__ __launch_bounds__(256) void reduce_row(
    const u64* __restrict__ rowp, const float* __restrict__ cb,
    float* __restrict__ zdec, int* __restrict__ rowidx)
{
  int tid = threadIdx.x;
  int base = blockIdx.x * 64;
  int n = base + (tid & 63);
  u64 best = ~0ULL;
  for (int p = tid >> 6; p < 4; p += 4)
    best = umin64(best, rowp[(size_t)p * 16384 + n]);
  __shared__ u64 s[4][64];
  __shared__ int sidx[64];
  s[tid >> 6][tid & 63] = best;
  __syncthreads();
  if (tid < 64){
    u64 b = umin64(umin64(s[0][tid], s[1][tid]), umin64(s[2][tid], s[3][tid]));
    int idx = (int)(b & 0xffffffffULL);
    idx = idx < 0 ? 0 : (idx > 8191 ? 8191 : idx);
    sidx[tid] = idx;
    rowidx[base + tid] = idx;
  }
  __syncthreads();
  for (int q = 0; q < 32; q++){
    int e = q * 256 + tid; int r = e >> 7, c = e & 127;
    zdec[(size_t)(base + r) * 128 + c] = cb[(size_t)sidx[r] * 128 + c];
  }
}

__global__ __launch_bounds__(256) void reduce_col(
    const u64* __restrict__ colp, const float* __restrict__ zenc, float* __restrict__ zembd)
{
  int tid = threadIdx.x;
  int base = blockIdx.x * 64;
  int n = base + (tid & 63);
  u64 best = ~0ULL;
  for (int p = tid >> 6; p < 128; p += 4)
    best = umin64(best, colp[(size_t)p * 8192 + n]);
  __shared__ u64 s[4][64];
  __shared__ int sidx[64];
  s[tid >> 6][tid & 63] = best;
  __syncthreads();
  if (tid < 64){
    u64 b = umin64(umin64(s[0][tid], s[1][tid]), umin64(s[2][tid], s[3][tid]));
    int idx = (int)(b & 0xffffffffULL);
    idx = idx < 0 ? 0 : (idx > 16383 ? 16383 : idx);
    sidx[tid] = idx;
  }
  __syncthreads();
  for (int q = 0; q < 32; q++){
    int e = q * 256 + tid; int r = e >> 7, c = e & 127;
    zembd[(size_t)(base + r) * 128 + c] = zenc[(size_t)sidx[r] * 128 + c];
  }
}

__global__ __launch_bounds__(256) void gather_xrec(
    const u16* __restrict__ xdecb, const int* __restrict__ rowidx, float* __restrict__ xrec)
{
  size_t o = (size_t)blockIdx.x * 256 + threadIdx.x;  // < 16384*784
  int row = (int)(o / 784), c = (int)(o % 784);
  int idx = rowidx[row];
  idx = idx < 0 ? 0 : (idx > 8191 ? 8191 : idx);
  xrec[o] = b2f(xdecb[(size_t)idx * 784 + c]);
}

// ---------------- launcher ----------------
extern "C" void kernel_launch(void* const* d_in, const int* in_sizes, int n_in,
                              void* d_out, int out_size, void* d_ws, size_t ws_size,
                              hipStream_t stream){
  const float* X   = (const float*)d_in[0];
  const float* w1  = (const float*)d_in[1];  const float* b1  = (const float*)d_in[2];
  const float* w2  = (const float*)d_in[3];  const float* b2  = (const float*)d_in[4];
  const float* w3  = (const float*)d_in[5];  const float* b3  = (const float*)d_in[6];
  const float* cb  = (const float*)d_in[7];
  const float* dw1 = (const float*)d_in[8];  const float* db1 = (const float*)d_in[9];
  const float* dw2 = (const float*)d_in[10]; const float* db2 = (const float*)d_in[11];
  const float* dw3 = (const float*)d_in[12]; const float* db3 = (const float*)d_in[13];

  float* out   = (float*)d_out;
  float* xrec  = out;                        // [16384*784] f32
  float* zenc  = out + 12845056;             // [16384*128]
  float* zdec  = zenc + 2097152;             // [16384*128]
  float* zembd = zdec + 2097152;             // [8192*128]

  const size_t NEEDED = 22085632;
  if (ws_size < NEEDED){
    canary_k<<<1, 256, 0, stream>>>(out, 1000.0f + (float)(ws_size >> 20));
    return;
  }

  // scratch inside d_out's xrec region (51.4 MB; xrec written only at the very end)
  char* ob = (char*)d_out;
  float* h1   = (float*)(ob + 0);            // 16384*512*4 = 33,554,432  [enc1 -> enc2]
  float* g2   = (float*)(ob + 0);            // 8192*512*4  = 16,777,216  [dec2 -> dec3]
  u16*   zhi  = (u16*)(ob + 33554432);       // 4,194,304                 [enc3 -> dist]
  u16*   zlo  = (u16*)(ob + 37748736);       // 4,194,304
  u16*   cbhi = (u16*)(ob + 41943040);       // 2,097,152                 [split -> dist]
  u16*   cblo = (u16*)(ob + 44040192);       // 2,097,152 -> 46,137,344 <= 51,380,224 OK

  char* w = (char*)d_ws;
  u16* W1Th = (u16*)(w + 0);        u16* W1Tl = (u16*)(w + 851968);
  u16* W2Th = (u16*)(w + 1703936);  u16* W2Tl = (u16*)(w + 1966080);
  u16* W3Th = (u16*)(w + 2228224);  u16* W3Tl = (u16*)(w + 2293760);
  u16* D1Th = (u16*)(w + 2359296);  u16* D1Tl = (u16*)(w + 2424832);
  u16* D2Th = (u16*)(w + 2490368);  u16* D2Tl = (u16*)(w + 2752512);
  u16* D3Th = (u16*)(w + 3014656);  u16* D3Tl = (u16*)(w + 3817472);   // -> 4,620,288
  float* q2f = (float*)(w + 4620288);        // 65,536
  float* t2f = (float*)(w + 4685824);        // 32,768
  int*  rowi = (int*)(w + 4718592);          // 65,536
  u64*  rowp = (u64*)(w + 4784128);          // 4*16384*8 = 524,288 -> 5,308,416
  // region R = [5,308,416, 22,085,632): h2 -> (colp, g1) -> xdecb
  float* h2   = (float*)(w + 5308416);       // 16384*256*4 = 16,777,216
  u64*  colp  = (u64*)(w + 5308416);         // 128*8192*8 = 8,388,608
  float* g1   = (float*)(w + 13697024);      // 8192*256*4 = 8,388,608
  u16*  xdecb = (u16*)(w + 5308416);         // 8192*784*2 = 12,845,056

  // prep
  prep_weights<<<4512, 256, 0, stream>>>(w1, w2, w3, dw1, dw2, dw3,
      W1Th, W1Tl, W2Th, W2Tl, W3Th, W3Tl, D1Th, D1Tl, D2Th, D2Tl, D3Th, D3Tl);
  split_cb<<<4096, 256, 0, stream>>>(cb, cbhi, cblo);

  // encoder (unchunked; 3-product split, f32 A staged+split on the fly)
  gemm_af32<1, 0><<<dim3(4, 128), 256, 0, stream>>>(X,  W1Th, W1Tl, b1, h1,   nullptr, nullptr, 784, 784, 832, 13, 512, 512);
  gemm_af32<1, 0><<<dim3(2, 128), 256, 0, stream>>>(h1, W2Th, W2Tl, b2, h2,   nullptr, nullptr, 512, 512, 512,  8, 256, 256);
  gemm_af32<0, 1><<<dim3(1, 128), 256, 0, stream>>>(h2, W3Th, W3Tl, b3, zenc, zhi,     zlo,     256, 256, 256,  4, 128, 128);

  // norms
  norms_all<<<96, 256, 0, stream>>>(zenc, cb, q2f, t2f);

  // fused distance + dual argmin (4 products, z in registers)
  dist3<<<dim3(4, 128), 256, 0, stream>>>(zhi, zlo, cbhi, cblo, q2f, t2f, rowp, colp);

  // reduces + gathers
  reduce_row<<<256, 256, 0, stream>>>(rowp, cb, zdec, rowi);
  reduce_col<<<128, 256, 0, stream>>>(colp, zenc, zembd);

  // decoder over 8192 codebook rows
  gemm_af32<1, 0><<<dim3(2, 64), 256, 0, stream>>>(cb, D1Th, D1Tl, db1, g1, nullptr, nullptr, 128, 128, 128, 2, 256, 256);
  gemm_af32<1, 0><<<dim3(4, 64), 256, 0, stream>>>(g1, D2Th, D2Tl, db2, g2, nullptr, nullptr, 256, 256, 256, 4, 512, 512);
  gemm_af32<2, 2><<<dim3(7, 64), 256, 0, stream>>>(g2, D3Th, D3Tl, db3, nullptr, xdecb, nullptr, 512, 512, 512, 8, 784, 784);

  gather_xrec<<<50176, 256, 0, stream>>>(xdecb, rowi, xrec);
}

// Round 8
// 595.595 us; speedup vs baseline: 40.0672x; 1.0864x over previous
//
#include <hip/hip_runtime.h>
#include <math.h>

using u16 = unsigned short;
using u32 = unsigned int;
using u64 = unsigned long long;

typedef __bf16 bf16x8 __attribute__((ext_vector_type(8)));
typedef short  s16x8  __attribute__((ext_vector_type(8)));
typedef float  f32x4  __attribute__((ext_vector_type(4)));

__device__ __forceinline__ float b2f(u16 u){
  union { u32 i; float f; } x; x.i = ((u32)u) << 16; return x.f;
}
__device__ __forceinline__ u16 f2b(float f){   // round-to-nearest-even
  union { float f; u32 i; } x; x.f = f;
  u32 i = x.i;
  u32 r = (i + 0x7fffu + ((i >> 16) & 1u)) >> 16;
  return (u16)r;
}
__device__ __forceinline__ f32x4 mfma16(s16x8 a, s16x8 b, f32x4 c){
  return __builtin_amdgcn_mfma_f32_16x16x32_bf16(
      __builtin_bit_cast(bf16x8, a), __builtin_bit_cast(bf16x8, b), c, 0, 0, 0);
}
__device__ __forceinline__ u64 shfl_xor_u64(u64 v, int m){
  int lo = __shfl_xor((int)(u32)v, m);
  int hi = __shfl_xor((int)(u32)(v >> 32), m);
  return ((u64)(u32)hi << 32) | (u32)lo;
}
__device__ __forceinline__ u64 umin64(u64 a, u64 b){ return a < b ? a : b; }
__device__ __forceinline__ u64 packmin(float v, int idx){
  u32 b = __float_as_uint(v);
  b = (b & 0x80000000u) ? ~b : (b | 0x80000000u);
  return ((u64)b << 32) | (u32)idx;
}

// ---------------- canary ----------------
__global__ __launch_bounds__(256) void canary_k(float* out, float code){
  out[threadIdx.x] = code;
}

// ---------------- fused prep: 6 transposed weight splits + cb split ----------------
__global__ __launch_bounds__(256) void prep_weights(
    const float* __restrict__ w1, const float* __restrict__ w2, const float* __restrict__ w3,
    const float* __restrict__ dw1, const float* __restrict__ dw2, const float* __restrict__ dw3,
    const float* __restrict__ cb,
    u16* __restrict__ o1h, u16* __restrict__ o1l, u16* __restrict__ o2h, u16* __restrict__ o2l,
    u16* __restrict__ o3h, u16* __restrict__ o3l, u16* __restrict__ o4h, u16* __restrict__ o4l,
    u16* __restrict__ o5h, u16* __restrict__ o5l, u16* __restrict__ o6h, u16* __restrict__ o6l,
    u16* __restrict__ cbh, u16* __restrict__ cbl)
{
  size_t o = (size_t)blockIdx.x * 256 + threadIdx.x;
  if (o >= 1155072){                       // cb segment: plain elementwise split
    size_t e = o - 1155072;
    if (e >= 1048576) return;
    float v = cb[e];
    u16 h = f2b(v);
    cbh[e] = h;
    cbl[e] = f2b(v - b2f(h));
    return;
  }
  const float* src; u16 *hi, *lo; int K, N, Kp; size_t base;
  if      (o <  425984){ src=w1;  hi=o1h; lo=o1l; K=784; N=512; Kp=832; base=0; }
  else if (o <  557056){ src=w2;  hi=o2h; lo=o2l; K=512; N=256; Kp=512; base=425984; }
  else if (o <  589824){ src=w3;  hi=o3h; lo=o3l; K=256; N=128; Kp=256; base=557056; }
  else if (o <  622592){ src=dw1; hi=o4h; lo=o4l; K=128; N=256; Kp=128; base=589824; }
  else if (o <  753664){ src=dw2; hi=o5h; lo=o5l; K=256; N=512; Kp=256; base=622592; }
  else                 { src=dw3; hi=o6h; lo=o6l; K=512; N=784; Kp=512; base=753664; }
  size_t e = o - base;
  int n = (int)(e / Kp), kp = (int)(e % Kp);
  u16 h = 0, l = 0;
  if (kp < K){
    float v = src[(size_t)kp * N + n];
    h = f2b(v);
    l = f2b(v - b2f(h));
  }
  hi[e] = h; lo[e] = l;
}

// ---------------- fused norms: q2 (z rows) + t2 (cb rows) ----------------
__global__ __launch_bounds__(256) void norms_all(const float* __restrict__ z, const float* __restrict__ cb,
                                                 float* __restrict__ q2, float* __restrict__ t2){
  int i = blockIdx.x * 256 + threadIdx.x;   // < 24576
  const float* src; float* dst;
  if (i < 16384){ src = z + (size_t)i * 128; dst = q2 + i; }
  else { int j = i - 16384; src = cb + (size_t)j * 128; dst = t2 + j; }
  const float4* r = (const float4*)src;
  float s = 0.f;
  for (int k = 0; k < 32; k++){
    float4 p = r[k];
    s += p.x * p.x + p.y * p.y + p.z * p.z + p.w * p.w;
  }
  *dst = s;
}

// ---------------- MFMA GEMM, A = f32 with on-the-fly hi/lo split ----------------
// 3 products: Ahi*Bhi + Ahi*Blo + Alo*Bhi.
// ACT: 0 none, 1 relu, 2 sigmoid(relu). OUTP: 0 f32; 1 f32 + hi/lo planes; 2 bf16 only.
template<int ACT, int OUTP>
__global__ __launch_bounds__(256, 2) void gemm_af32(
    const float* __restrict__ A, const u16* __restrict__ B0, const u16* __restrict__ B1,
    const float* __restrict__ bias, float* __restrict__ Cf,
    u16* __restrict__ P0, u16* __restrict__ P1,
    int Astr, int KLIM, int Kp, int KT, int N, int nRowsB)
{
  __shared__ __align__(16) u16 Ah[128][72];
  __shared__ __align__(16) u16 Al[128][72];
  __shared__ __align__(16) u16 Bh[128][72];
  __shared__ __align__(16) u16 Bl[128][72];
  const int tid = threadIdx.x;
  const int m0 = blockIdx.y * 128, n0 = blockIdx.x * 128;
  const int wave = tid >> 6, lane = tid & 63;
  const int wm = (wave >> 1) * 64, wn = (wave & 1) * 64;
  const int quad = lane >> 4, l15 = lane & 15;
  f32x4 acc[4][4] = {};

  for (int kt = 0; kt < KT; ++kt){
    const int kb = kt * 64;
    #pragma unroll
    for (int c = 0; c < 8; c++){            // stage A: 128 x 64 f32, split hi/lo
      int idx = c * 256 + tid;
      int r = idx >> 4, c4 = (idx & 15) * 4;
      float4 v = make_float4(0.f, 0.f, 0.f, 0.f);
      if (kb + c4 < KLIM)
        v = *(const float4*)(A + (size_t)(m0 + r) * Astr + kb + c4);
      ushort4 h, l;
      h.x = f2b(v.x); l.x = f2b(v.x - b2f(h.x));
      h.y = f2b(v.y); l.y = f2b(v.y - b2f(h.y));
      h.z = f2b(v.z); l.z = f2b(v.z - b2f(h.z));
      h.w = f2b(v.w); l.w = f2b(v.w - b2f(h.w));
      *(ushort4*)&Ah[r][c4] = h;
      *(ushort4*)&Al[r][c4] = l;
    }
    #pragma unroll
    for (int c = 0; c < 4; c++){            // stage B planes: 128 x 64 u16 each
      int idx = c * 256 + tid;
      int r = idx >> 3, col = (idx & 7) * 8;
      int rb = n0 + r; rb = rb < nRowsB ? rb : nRowsB - 1;
      *(uint4*)&Bh[r][col] = *(const uint4*)(B0 + (size_t)rb * Kp + kb + col);
      *(uint4*)&Bl[r][col] = *(const uint4*)(B1 + (size_t)rb * Kp + kb + col);
    }
    __syncthreads();
    #pragma unroll
    for (int kh = 0; kh < 2; ++kh){
      s16x8 ah[4], al[4], bh[4], bl[4];
      #pragma unroll
      for (int t4 = 0; t4 < 4; t4++){
        ah[t4] = *(const s16x8*)&Ah[wm + t4 * 16 + l15][kh * 32 + quad * 8];
        al[t4] = *(const s16x8*)&Al[wm + t4 * 16 + l15][kh * 32 + quad * 8];
        bh[t4] = *(const s16x8*)&Bh[wn + t4 * 16 + l15][kh * 32 + quad * 8];
        bl[t4] = *(const s16x8*)&Bl[wn + t4 * 16 + l15][kh * 32 + quad * 8];
      }
      #pragma unroll
      for (int mt = 0; mt < 4; mt++)
        #pragma unroll
        for (int nt = 0; nt < 4; nt++){
          acc[mt][nt] = mfma16(ah[mt], bh[nt], acc[mt][nt]);
          acc[mt][nt] = mfma16(ah[mt], bl[nt], acc[mt][nt]);
          acc[mt][nt] = mfma16(al[mt], bh[nt], acc[mt][nt]);
        }
    }
    __syncthreads();
  }

  float bvs[4]; int cols[4];
  #pragma unroll
  for (int nt = 0; nt < 4; nt++){
    int cN = n0 + wn + nt * 16 + l15;
    cols[nt] = cN;
    int cc = cN < N ? cN : N - 1;
    bvs[nt] = bias[cc];
  }
  #pragma unroll
  for (int mt = 0; mt < 4; mt++){
    int rbase = m0 + wm + mt * 16 + quad * 4;
    #pragma unroll
    for (int nt = 0; nt < 4; nt++){
      if (cols[nt] < N){
        #pragma unroll
        for (int r = 0; r < 4; r++){
          float v = acc[mt][nt][r] + bvs[nt];
          if (ACT >= 1) v = v > 0.f ? v : 0.f;
          if (ACT == 2) v = 1.f / (1.f + expf(-v));
          size_t off = (size_t)(rbase + r) * N + cols[nt];
          if (OUTP == 2){
            P0[off] = f2b(v);
          } else {
            Cf[off] = v;
            if (OUTP == 1){
              u16 h = f2b(v);
              P0[off] = h;
              P1[off] = f2b(v - b2f(h));
            }
          }
        }
      }
    }
  }
}

// ---------------- dist v4: barrier-free j-sweep, per-wave col partials ----------------
// grid (4 strips, 128 i-tiles); each block sweeps 16 j-tiles of 128 (strip stride 2048).
// colp gets 256 partial rows: [iblk*2 + wavepair][8192].
__global__ __launch_bounds__(256, 1) void dist3(
    const u16* __restrict__ Zh, const u16* __restrict__ Zl,
    const u16* __restrict__ Bh, const u16* __restrict__ Bl,
    const float* __restrict__ q2, const float* __restrict__ t2,
    u64* __restrict__ rowp, u64* __restrict__ colp)
{
  __shared__ u64 sRow[2][128];
  const int tid = threadIdx.x;
  const int i0 = blockIdx.y * 128;
  const int strip = blockIdx.x;
  const int wave = tid >> 6, lane = tid & 63;
  const int wm = (wave >> 1) * 64, wn = (wave & 1) * 64;
  const int quad = lane >> 4, l15 = lane & 15;

  // z fragments, loaded once
  s16x8 zh[2][2][4], zl[2][2][4];
  #pragma unroll
  for (int kb = 0; kb < 2; kb++)
    #pragma unroll
    for (int kh = 0; kh < 2; kh++)
      #pragma unroll
      for (int mt = 0; mt < 4; mt++){
        size_t off = (size_t)(i0 + wm + mt * 16 + l15) * 128 + kb * 64 + kh * 32 + quad * 8;
        zh[kb][kh][mt] = *(const s16x8*)(Zh + off);
        zl[kb][kh][mt] = *(const s16x8*)(Zl + off);
      }
  float qv[4][4];
  #pragma unroll
  for (int mt = 0; mt < 4; mt++)
    #pragma unroll
    for (int r = 0; r < 4; r++)
      qv[mt][r] = q2[i0 + wm + mt * 16 + quad * 4 + r];

  u64 rowm[4][4];
  #pragma unroll
  for (int mt = 0; mt < 4; mt++)
    #pragma unroll
    for (int r = 0; r < 4; r++) rowm[mt][r] = ~0ULL;

  for (int jt = 0; jt < 16; ++jt){
    const int j0 = strip * 2048 + jt * 128;
    f32x4 acc[4][4] = {};
    #pragma unroll
    for (int kb = 0; kb < 2; kb++)
      #pragma unroll
      for (int kh = 0; kh < 2; kh++){
        s16x8 bh[4], bl[4];
        #pragma unroll
        for (int nt = 0; nt < 4; nt++){
          size_t off = (size_t)(j0 + wn + nt * 16 + l15) * 128 + kb * 64 + kh * 32 + quad * 8;
          bh[nt] = *(const s16x8*)(Bh + off);
          bl[nt] = *(const s16x8*)(Bl + off);
        }
        #pragma unroll
        for (int mt = 0; mt < 4; mt++)
          #pragma unroll
          for (int nt = 0; nt < 4; nt++){
            acc[mt][nt] = mfma16(zh[kb][kh][mt], bh[nt], acc[mt][nt]);
            acc[mt][nt] = mfma16(zh[kb][kh][mt], bl[nt], acc[mt][nt]);
            acc[mt][nt] = mfma16(zl[kb][kh][mt], bh[nt], acc[mt][nt]);
            acc[mt][nt] = mfma16(zl[kb][kh][mt], bl[nt], acc[mt][nt]);
          }
      }
    float t2v[4]; int gj[4];
    #pragma unroll
    for (int nt = 0; nt < 4; nt++){
      gj[nt] = j0 + wn + nt * 16 + l15;
      t2v[nt] = t2[gj[nt]];
    }
    // row: per (mt,r) float scan over nt (gj ascending => first-wins), one pack+umin per tile
    #pragma unroll
    for (int mt = 0; mt < 4; mt++){
      #pragma unroll
      for (int r = 0; r < 4; r++){
        float qq = qv[mt][r];
        float rbest = (qq - 2.f * acc[mt][0][r]) + t2v[0];
        int   ridx  = gj[0];
        #pragma unroll
        for (int nt = 1; nt < 4; nt++){
          float v = (qq - 2.f * acc[mt][nt][r]) + t2v[nt];
          if (v < rbest){ rbest = v; ridx = gj[nt]; }
        }
        rowm[mt][r] = umin64(rowm[mt][r], packmin(rbest, ridx));
      }
    }
    // col: per nt float scan over (mt,r) (gi ascending), cross-quad shuffle, per-wave write
    #pragma unroll
    for (int nt = 0; nt < 4; nt++){
      float cbest = 3.4e38f; int cidx = 0;
      #pragma unroll
      for (int mt = 0; mt < 4; mt++){
        #pragma unroll
        for (int r = 0; r < 4; r++){
          float vc = (t2v[nt] - 2.f * acc[mt][nt][r]) + qv[mt][r];
          if (vc < cbest){ cbest = vc; cidx = i0 + wm + mt * 16 + quad * 4 + r; }
        }
      }
      u64 p = packmin(cbest, cidx);
      p = umin64(p, shfl_xor_u64(p, 16));
      p = umin64(p, shfl_xor_u64(p, 32));
      if (quad == 0)
        colp[(size_t)(blockIdx.y * 2 + (wave >> 1)) * 8192 + gj[nt]] = p;
    }
  }

  // row final reduce (single barrier at kernel end)
  #pragma unroll
  for (int mt = 0; mt < 4; mt++)
    #pragma unroll
    for (int r = 0; r < 4; r++){
      u64 p = rowm[mt][r];
      p = umin64(p, shfl_xor_u64(p, 1));
      p = umin64(p, shfl_xor_u64(p, 2));
      p = umin64(p, shfl_xor_u64(p, 4));
      p = umin64(p, shfl_xor_u64(p, 8));
      rowm[mt][r] = p;
    }
  if (l15 == 0){
    #pragma unroll
    for (int mt = 0; mt < 4; mt++)
      #pragma unroll
      for (int r = 0; r < 4; r++)
        sRow[wave & 1][wm + mt * 16 + quad * 4 + r] = rowm[mt][r];
  }
  __syncthreads();
  if (tid < 128)
    rowp[(size_t)strip * 16384 + i0 + tid] = umin64(sRow[0][tid], sRow[1][tid]);
}

// ---------------- merged final reduces + gathers ----------------
// blocks [0,256): row side (rowp 4 partials -> zdec+rowidx); [256,384): col side (colp 256 partials -> zembd)
__global__ __launch_bounds__(256) void reduce_rc(
    const u64* __restrict__ rowp, const u64* __restrict__ colp,
    const float* __restrict__ cb, const float* __restrict__ zenc,
    float* __restrict__ zdec, float* __restrict__ zembd, int* __restrict__ rowidx)
{
  int tid = threadIdx.x;
  __shared__ u64 s[4][64];
  __shared__ int sidx[64];
  if (blockIdx.x < 256){
    int base = blockIdx.x * 64;
    int n = base + (tid & 63);
    u64 best = ~0ULL;
    for (int p = tid >> 6; p < 4; p += 4)
      best = umin64(best, rowp[(size_t)p * 16384 + n]);
    s[tid >> 6][tid & 63] = best;
    __syncthreads();
    if (tid < 64){
      u64 b = umin64(umin64(s[0][tid], s[1][tid]), umin64(s[2][tid], s[3][tid]));
      int idx = (int)(b & 0xffffffffULL);
      idx = idx < 0 ? 0 : (idx > 8191 ? 8191 : idx);
      sidx[tid] = idx;
      rowidx[base + tid] = idx;
    }
    __syncthreads();
    for (int q = 0; q < 32; q++){
      int e = q * 256 + tid; int r = e >> 7, c = e & 127;
      zdec[(size_t)(base + r) * 128 + c] = cb[(size_t)sidx[r] * 128 + c];
    }
  } else {
    int base = (blockIdx.x - 256) * 64;
    int n = base + (tid & 63);
    u64 best = ~0ULL;
    for (int p = tid >> 6; p < 256; p += 4)
      best = umin64(best, colp[(size_t)p * 8192 + n]);
    s[tid >> 6][tid & 63] = best;
    __syncthreads();
    if (tid < 64){
      u64 b = umin64(umin64(s[0][tid], s[1][tid]), umin64(s[2][tid], s[3][tid]));
      int idx = (int)(b & 0xffffffffULL);
      idx = idx < 0 ? 0 : (idx > 16383 ? 16383 : idx);
      sidx[tid] = idx;
    }
    __syncthreads();
    for (int q = 0; q < 32; q++){
      int e = q * 256 + tid; int r = e >> 7, c = e & 127;
      zembd[(size_t)(base + r) * 128 + c] = zenc[(size_t)sidx[r] * 128 + c];
    }
  }
}

__global__ __launch_bounds__(256) void gather_xrec(
    const u16* __restrict__ xdecb, const int* __restrict__ rowidx, float* __restrict__ xrec)
{
  size_t o = (size_t)blockIdx.x * 256 + threadIdx.x;  // < 16384*784
  int row = (int)(o / 784), c = (int)(o % 784);
  int idx = rowidx[row];
  idx = idx < 0 ? 0 : (idx > 8191 ? 8191 : idx);
  xrec[o] = b2f(xdecb[(size_t)idx * 784 + c]);
}

// ---------------- launcher ----------------
extern "C" void kernel_launch(void* const* d_in, const int* in_sizes, int n_in,
                              void* d_out, int out_size, void* d_ws, size_t ws_size,
                              hipStream_t stream){
  const float* X   = (const float*)d_in[0];
  const float* w1  = (const float*)d_in[1];  const float* b1  = (const float*)d_in[2];
  const float* w2  = (const float*)d_in[3];  const float* b2  = (const float*)d_in[4];
  const float* w3  = (const float*)d_in[5];  const float* b3  = (const float*)d_in[6];
  const float* cb  = (const float*)d_in[7];
  const float* dw1 = (const float*)d_in[8];  const float* db1 = (const float*)d_in[9];
  const float* dw2 = (const float*)d_in[10]; const float* db2 = (const float*)d_in[11];
  const float* dw3 = (const float*)d_in[12]; const float* db3 = (const float*)d_in[13];

  float* out   = (float*)d_out;
  float* xrec  = out;                        // [16384*784] f32
  float* zenc  = out + 12845056;             // [16384*128]
  float* zdec  = zenc + 2097152;             // [16384*128]
  float* zembd = zdec + 2097152;             // [8192*128]

  const size_t NEEDED = 22085632;
  if (ws_size < NEEDED){
    canary_k<<<1, 256, 0, stream>>>(out, 1000.0f + (float)(ws_size >> 20));
    return;
  }

  // scratch inside d_out's xrec region (51.4 MB; xrec written only at the very end)
  char* ob = (char*)d_out;
  float* h1   = (float*)(ob + 0);            // 16384*512*4 = 33,554,432  [enc1 -> enc2]
  float* g2   = (float*)(ob + 0);            // 8192*512*4  = 16,777,216  [dec2 -> dec3]
  u16*   zhi  = (u16*)(ob + 33554432);       // 4,194,304                 [enc3 -> dist]
  u16*   zlo  = (u16*)(ob + 37748736);       // 4,194,304
  u16*   cbhi = (u16*)(ob + 41943040);       // 2,097,152                 [prep -> dist]
  u16*   cblo = (u16*)(ob + 44040192);       // 2,097,152 -> 46,137,344 <= 51,380,224 OK

  char* w = (char*)d_ws;
  u16* W1Th = (u16*)(w + 0);        u16* W1Tl = (u16*)(w + 851968);
  u16* W2Th = (u16*)(w + 1703936);  u16* W2Tl = (u16*)(w + 1966080);
  u16* W3Th = (u16*)(w + 2228224);  u16* W3Tl = (u16*)(w + 2293760);
  u16* D1Th = (u16*)(w + 2359296);  u16* D1Tl = (u16*)(w + 2424832);
  u16* D2Th = (u16*)(w + 2490368);  u16* D2Tl = (u16*)(w + 2752512);
  u16* D3Th = (u16*)(w + 3014656);  u16* D3Tl = (u16*)(w + 3817472);   // -> 4,620,288
  float* q2f = (float*)(w + 4620288);        // 65,536
  float* t2f = (float*)(w + 4685824);        // 32,768
  int*  rowi = (int*)(w + 4718592);          // 65,536
  u64*  rowp = (u64*)(w + 4784128);          // 4*16384*8 = 524,288 -> 5,308,416
  // region R = [5,308,416, 22,085,632): h2 -> colp(256 partials) -> (g1, xdecb)
  float* h2   = (float*)(w + 5308416);       // 16384*256*4 = 16,777,216
  u64*  colp  = (u64*)(w + 5308416);         // 256*8192*8 = 16,777,216 -> 22,085,632
  float* g1   = (float*)(w + 13697024);      // 8192*256*4 = 8,388,608 (after colp consumed)
  u16*  xdecb = (u16*)(w + 5308416);         // 8192*784*2 = 12,845,056 (after colp consumed)

  // prep (weights + codebook split, one kernel)
  prep_weights<<<8608, 256, 0, stream>>>(w1, w2, w3, dw1, dw2, dw3, cb,
      W1Th, W1Tl, W2Th, W2Tl, W3Th, W3Tl, D1Th, D1Tl, D2Th, D2Tl, D3Th, D3Tl, cbhi, cblo);

  // encoder (unchunked; 3-product split, f32 A staged+split on the fly)
  gemm_af32<1, 0><<<dim3(4, 128), 256, 0, stream>>>(X,  W1Th, W1Tl, b1, h1,   nullptr, nullptr, 784, 784, 832, 13, 512, 512);
  gemm_af32<1, 0><<<dim3(2, 128), 256, 0, stream>>>(h1, W2Th, W2Tl, b2, h2,   nullptr, nullptr, 512, 512, 512,  8, 256, 256);
  gemm_af32<0, 1><<<dim3(1, 128), 256, 0, stream>>>(h2, W3Th, W3Tl, b3, zenc, zhi,     zlo,     256, 256, 256,  4, 128, 128);

  // norms
  norms_all<<<96, 256, 0, stream>>>(zenc, cb, q2f, t2f);

  // fused distance + dual argmin (4 products, z in registers, barrier-free sweep)
  dist3<<<dim3(4, 128), 256, 0, stream>>>(zhi, zlo, cbhi, cblo, q2f, t2f, rowp, colp);

  // merged reduces + gathers
  reduce_rc<<<384, 256, 0, stream>>>(rowp, colp, cb, zenc, zdec, zembd, rowi);

  // decoder over 8192 codebook rows
  gemm_af32<1, 0><<<dim3(2, 64), 256, 0, stream>>>(cb, D1Th, D1Tl, db1, g1, nullptr, nullptr, 128, 128, 128, 2, 256, 256);
  gemm_af32<1, 0><<<dim3(4, 64), 256, 0, stream>>>(g1, D2Th, D2Tl, db2, g2, nullptr, nullptr, 256, 256, 256, 4, 512, 512);
  gemm_af32<2, 2><<<dim3(7, 64), 256, 0, stream>>>(g2, D3Th, D3Tl, db3, nullptr, xdecb, nullptr, 512, 512, 512, 8, 784, 784);

  gather_xrec<<<50176, 256, 0, stream>>>(xdecb, rowi, xrec);
}